// Round 1
// baseline (1500.052 us; speedup 1.0000x reference)
//
#include <hip/hip_runtime.h>

typedef unsigned long long ull;
typedef __attribute__((ext_vector_type(8))) short bf16x8;
typedef __attribute__((ext_vector_type(4))) float f32x4;

// ---------- helpers ----------
__device__ __forceinline__ unsigned short bf16b(float x){
    unsigned u = __float_as_uint(x);
    unsigned r = (u + 0x7FFFu + ((u >> 16) & 1u)) >> 16;
    return (unsigned short)r;
}
__device__ __forceinline__ float b2f(unsigned short u){
    return __uint_as_float(((unsigned)u) << 16);
}
__device__ __forceinline__ void st4(unsigned short* p, f32x4 v){
    ull pk = (ull)bf16b(v[0]) | (((ull)bf16b(v[1])) << 16)
           | (((ull)bf16b(v[2])) << 32) | (((ull)bf16b(v[3])) << 48);
    *(ull*)p = pk;
}
__device__ __forceinline__ f32x4 ld4(const unsigned short* p){
    ull pk = *(const ull*)p;
    f32x4 v;
    v[0] = b2f((unsigned short)pk);
    v[1] = b2f((unsigned short)(pk >> 16));
    v[2] = b2f((unsigned short)(pk >> 32));
    v[3] = b2f((unsigned short)(pk >> 48));
    return v;
}

// u64 DPP min reduction (KNN). All-lane valid, row_mask 0xF safe.
#define DPPMIN(k, ctrl) do { \
    unsigned _lo = (unsigned)(k), _hi = (unsigned)((k) >> 32); \
    unsigned _l2 = (unsigned)__builtin_amdgcn_update_dpp((int)_lo, (int)_lo, (ctrl), 0xF, 0xF, false); \
    unsigned _h2 = (unsigned)__builtin_amdgcn_update_dpp((int)_hi, (int)_hi, (ctrl), 0xF, 0xF, false); \
    ull _k2 = (((ull)_h2) << 32) | _l2; \
    if (_k2 < (k)) (k) = _k2; \
} while (0)
// ctrl codes: quad_perm(1,0,3,2)=0xB1, quad_perm(2,3,0,1)=0x4E,
// row_half_mirror=0x141, row_mirror=0x140, row_bcast15=0x142, row_bcast31=0x143

// u32 DPP max step (FPS): nonneg float bits compare as u32
#define DPPMAXU32(mb, ctrl) do { \
    unsigned _o = (unsigned)__builtin_amdgcn_update_dpp((int)(mb), (int)(mb), (ctrl), 0xF, 0xF, false); \
    if (_o > (mb)) (mb) = _o; \
} while (0)

// XOR-swizzled LDS layout for row-major [rows][K*?] bf16 tiles, K-width = KT*32.
template<int KT>
__device__ __forceinline__ int swz(int r, int c){
    return r * (KT * 32) + ((((c >> 3) + r) & (KT * 4 - 1)) << 3) + (c & 7);
}

// D[ch][row] += W^T[ch][k] * data[row][k]; A from global (row-major [ch][K]),
// B from swizzled LDS (row-major [row][K]). Wave covers 64 ch (mt 0..3) x 64 rows (nt 0..3).
template<int KT>
__device__ __forceinline__ void gemmT(const unsigned short* __restrict__ Wt,
                                      const unsigned short* __restrict__ Blds,
                                      int ch0, int lane, f32x4 acc[4][4])
{
    int i = lane & 15, q = lane >> 4;
#pragma unroll
    for (int kt = 0; kt < KT; kt++){
        int k0 = kt * 32 + q * 8;
        bf16x8 bfr[4], afr[4];
#pragma unroll
        for (int nt = 0; nt < 4; nt++)
            bfr[nt] = *(const bf16x8*)(Blds + swz<KT>(nt * 16 + i, k0));
#pragma unroll
        for (int mt = 0; mt < 4; mt++)
            afr[mt] = *(const bf16x8*)(Wt + (size_t)(ch0 + mt * 16 + i) * (KT * 32) + k0);
#pragma unroll
        for (int mt = 0; mt < 4; mt++)
#pragma unroll
            for (int nt = 0; nt < 4; nt++)
                acc[mt][nt] = __builtin_amdgcn_mfma_f32_16x16x32_bf16(afr[mt], bfr[nt], acc[mt][nt], 0, 0, 0);
    }
}

#define ZERO44(A) do { _Pragma("unroll") for (int _m = 0; _m < 4; _m++) \
    { _Pragma("unroll") for (int _n = 0; _n < 4; _n++) { A[_m][_n][0]=0.f;A[_m][_n][1]=0.f;A[_m][_n][2]=0.f;A[_m][_n][3]=0.f; } } } while(0)

// ---------- kernel 0a: weight transposes / bf16 conversion ----------
__global__ __launch_bounds__(256) void prep_weights(
    const float* __restrict__ wq, const float* __restrict__ wk, const float* __restrict__ wv,
    const float* __restrict__ dw2, const float* __restrict__ gw1, const float* __restrict__ gw2,
    const float* __restrict__ lw,
    float* __restrict__ wqT, unsigned short* __restrict__ wkT, unsigned short* __restrict__ wvT,
    unsigned short* __restrict__ dw2T, unsigned short* __restrict__ gw1T,
    unsigned short* __restrict__ gw2T, unsigned short* __restrict__ lwT)
{
    int i = blockIdx.x * 256 + threadIdx.x;
    if (i < 32768){ int n = i >> 7, k = i & 127; wqT[i] = wq[k * 256 + n]; return; } i -= 32768;
    if (i < 32768){ int n = i >> 7, k = i & 127; wkT[i] = bf16b(wk[k * 256 + n]); return; } i -= 32768;
    if (i < 32768){ int n = i >> 7, k = i & 127; wvT[i] = bf16b(wv[k * 256 + n]); return; } i -= 32768;
    if (i < 65536){ int n = i >> 8, k = i & 255; dw2T[i] = bf16b(dw2[k * 256 + n]); return; } i -= 65536;
    if (i < 65536){ int n = i >> 8, k = i & 255; gw1T[i] = bf16b(gw1[k * 256 + n]); return; } i -= 65536;
    if (i < 65536){ int n = i >> 8, k = i & 255; gw2T[i] = bf16b(gw2[k * 256 + n]); return; } i -= 65536;
    if (i < 65536){ int n = i >> 8, k = i & 255; lwT[i]  = bf16b(lw[k * 256 + n]); return; }
}

// ---------- kernel 0b: points -> bf16 ----------
__global__ __launch_bounds__(256) void cvt_points(const float* __restrict__ pts,
                                                  unsigned short* __restrict__ out)
{
    int i = (blockIdx.x * 256 + threadIdx.x) * 4;
    f32x4 v = *(const f32x4*)(pts + i);
    ull pk = (ull)bf16b(v[0]) | (((ull)bf16b(v[1])) << 16)
           | (((ull)bf16b(v[2])) << 32) | (((ull)bf16b(v[3])) << 48);
    *(ull*)(out + i) = pk;
}

// ---------- kernel 1: farthest point sampling (exact, numpy-faithful) ----------
// 256 threads = 4 waves (1/SIMD), 16 pts/lane. Per step:
//   exact 9-op distance update (no per-point key math), per-lane fmax tree,
//   4-stage u32 DPP row-max + readlane + scalar max -> wave max (SGPR),
//   ballot first-match -> smallest winning index, single LDS atomicMax on
//   (valbits<<32 | ~p) into a 3-slot rotating buffer (race-free reset with
//   one barrier per step). Global stores moved out of the serial loop.
__global__ __launch_bounds__(256) void fps_kernel(const float* __restrict__ xyz,
                                                  float* __restrict__ nxyz_out,
                                                  int* __restrict__ fps_idx)
{
    __shared__ float sx[4096], sy[4096], sz[4096];
    __shared__ int farS[1024];
    __shared__ ull aslot[3];
    int b = blockIdx.x, t = threadIdx.x;
    int lane = t & 63;
    for (int p = t; p < 4096; p += 256){
        const float* s = xyz + ((size_t)b * 4096 + p) * 3;
        sx[p] = s[0]; sy[p] = s[1]; sz[p] = s[2];
    }
    if (t < 3) aslot[t] = 0;
    __syncthreads();
    float px[16], py[16], pz[16], dist[16];
#pragma unroll
    for (int j = 0; j < 16; j++){
        int p = t + (j << 8);
        px[j] = sx[p]; py[j] = sy[p]; pz[j] = sz[p];
        dist[j] = 1e10f;
    }
    int far = 0;
    int ka = 0;
    for (int s = 0; s < 1024; s++){
        if (t == 0) farS[s] = far;
        float cx = sx[far], cy = sy[far], cz = sz[far];
#pragma unroll
        for (int j = 0; j < 16; j++){
            float dx = __fsub_rn(px[j], cx);
            float dy = __fsub_rn(py[j], cy);
            float dz = __fsub_rn(pz[j], cz);
            float d = __fadd_rn(__fadd_rn(__fmul_rn(dx, dx), __fmul_rn(dy, dy)), __fmul_rn(dz, dz));
            dist[j] = fminf(dist[j], d);
        }
        // per-lane max over 16 (tree)
        float m8[8];
#pragma unroll
        for (int j = 0; j < 8; j++) m8[j] = fmaxf(dist[2 * j], dist[2 * j + 1]);
#pragma unroll
        for (int j = 0; j < 4; j++) m8[j] = fmaxf(m8[2 * j], m8[2 * j + 1]);
        float mx = fmaxf(fmaxf(m8[0], m8[1]), fmaxf(m8[2], m8[3]));
        unsigned mb = __float_as_uint(mx);      // nonneg: u32 order == f32 order
        // 16-lane row max via DPP butterfly
        DPPMAXU32(mb, 0xB1); DPPMAXU32(mb, 0x4E);
        DPPMAXU32(mb, 0x141); DPPMAXU32(mb, 0x140);
        // wave max: 4 row maxes -> SGPR
        unsigned r0 = (unsigned)__builtin_amdgcn_readlane((int)mb, 0);
        unsigned r1 = (unsigned)__builtin_amdgcn_readlane((int)mb, 16);
        unsigned r2 = (unsigned)__builtin_amdgcn_readlane((int)mb, 32);
        unsigned r3 = (unsigned)__builtin_amdgcn_readlane((int)mb, 48);
        unsigned wa = r0 > r1 ? r0 : r1;
        unsigned wb = r2 > r3 ? r2 : r3;
        unsigned wm = wa > wb ? wa : wb;
        // smallest p in this wave achieving wm (j ascending = p ascending; ctz = lowest lane)
        unsigned psel = 0;
#pragma unroll
        for (int j = 0; j < 16; j++){
            ull mk = __ballot(__float_as_uint(dist[j]) == wm);
            if (mk){
                psel = (unsigned)((t & 0xC0u) + (unsigned)__builtin_ctzll(mk) + (unsigned)(j << 8));
                break;
            }
        }
        ull key = (((ull)wm) << 32) | (ull)(~psel);
        if (lane == 0) atomicMax(&aslot[ka], key);
        int kn = ka + 1; if (kn == 3) kn = 0;
        if (t == 0) aslot[kn] = 0;              // slot for next step; read-window closed
        __syncthreads();
        far = (int)(~(unsigned)aslot[ka]);
        ka = kn;
    }
    // write outputs once (off the serial critical path)
    float* outp = nxyz_out + (size_t)b * 3072;
    for (int s2 = t; s2 < 1024; s2 += 256){
        int f = farS[s2];
        fps_idx[b * 1024 + s2] = f;
        outp[s2 * 3 + 0] = sx[f];
        outp[s2 * 3 + 1] = sy[f];
        outp[s2 * 3 + 2] = sz[f];
    }
}

// ---------- kernel 2: KNN (16 smallest d2 per sampled point) ----------
__global__ __launch_bounds__(256) void knn_kernel(const float* __restrict__ xyz,
                                                  const float* __restrict__ nxyz,
                                                  int* __restrict__ knn_idx)
{
    __shared__ float d2s[4096];
    __shared__ ull kslot[4];
    int G = blockIdx.x; int b = G >> 10;
    int t = threadIdx.x, lane = t & 63, wv = t >> 6;
    float qx = nxyz[(size_t)G * 3], qy = nxyz[(size_t)G * 3 + 1], qz = nxyz[(size_t)G * 3 + 2];
    float qq = qx * qx + qy * qy + qz * qz;
    for (int j = 0; j < 16; j++){
        int p = t + (j << 8);
        const float* s = xyz + ((size_t)b * 4096 + p) * 3;
        float x = s[0], y = s[1], z = s[2];
        d2s[p] = qq - 2.f * (qx * x + qy * y + qz * z) + (x * x + y * y + z * z);
    }
    __syncthreads();
    for (int r = 0; r < 16; r++){
        ull best = ~0ull;
#pragma unroll
        for (int j = 0; j < 16; j++){
            int p = t + (j << 8);
            unsigned bb = __float_as_uint(d2s[p]);
            bb = (bb & 0x80000000u) ? ~bb : (bb | 0x80000000u);
            ull key = (((ull)bb) << 32) | (unsigned)p;
            if (key < best) best = key;
        }
        DPPMIN(best, 0xB1); DPPMIN(best, 0x4E); DPPMIN(best, 0x141);
        DPPMIN(best, 0x140); DPPMIN(best, 0x142); DPPMIN(best, 0x143);
        if (lane == 63) kslot[wv] = best;
        __syncthreads();
        if (t == 0){
            ull bk = kslot[0];
            for (int w = 1; w < 4; w++) if (kslot[w] < bk) bk = kslot[w];
            int p = (int)(unsigned)bk;
            knn_idx[(size_t)G * 16 + r] = p;
            d2s[p] = 3.0e38f;
        }
        __syncthreads();
    }
}

// ---------- kernel 3: q = sampled_points @ wq (f32) ----------
__global__ __launch_bounds__(256) void q_kernel(const float* __restrict__ points,
                                                const float* __restrict__ wqT,
                                                const int* __restrict__ fps_idx,
                                                float* __restrict__ qbuf)
{
    __shared__ float sp[8][128];
    int t = threadIdx.x;
    int g0 = blockIdx.x * 8;
    {
        int r = t >> 5, c = (t & 31) * 4;
        int G = g0 + r; int b = G >> 10; int p = fps_idx[G];
        const f32x4 v = *(const f32x4*)(points + ((size_t)b * 4096 + p) * 128 + c);
        *(f32x4*)&sp[r][c] = v;
    }
    __syncthreads();
    float acc[8] = {0.f,0.f,0.f,0.f,0.f,0.f,0.f,0.f};
    const float* wr = wqT + t * 128;
    for (int k = 0; k < 128; k += 4){
        f32x4 w = *(const f32x4*)(wr + k);
#pragma unroll
        for (int r = 0; r < 8; r++)
            acc[r] += w[0]*sp[r][k] + w[1]*sp[r][k+1] + w[2]*sp[r][k+2] + w[3]*sp[r][k+3];
    }
#pragma unroll
    for (int r = 0; r < 8; r++) qbuf[(size_t)(g0 + r) * 256 + t] = acc[r];
}

// ---------- kernel 4: fused attention stack (4 groups / block) ----------
__global__ __launch_bounds__(256, 2) void fused_attn(
    const unsigned short* __restrict__ pts16,
    const float* __restrict__ xyz, const float* __restrict__ nxyz,
    const int* __restrict__ knn_idx, const float* __restrict__ qbuf,
    const unsigned short* __restrict__ wkT, const unsigned short* __restrict__ wvT,
    const unsigned short* __restrict__ dw2T, const unsigned short* __restrict__ gw1T,
    const unsigned short* __restrict__ gw2T,
    const float* __restrict__ dw1, const float* __restrict__ db1,
    const float* __restrict__ db2, const float* __restrict__ gb1, const float* __restrict__ gb2,
    unsigned short* __restrict__ resY)
{
    __shared__ unsigned short bufA[16384];  // pos1 -> t -> a1 -> e   [64][256] swz<8>
    __shared__ unsigned short bufU[16384];  // ptsA(swz<4>) -> u(swz<8>)
    int t = threadIdx.x, lane = t & 63, wave = t >> 6;
    int i = lane & 15, q = lane >> 4;
    int G0 = blockIdx.x * 4;
    int ch0 = wave * 64;
    unsigned short* ptsA = bufU;
    float* dw1s  = (float*)(bufU + 8192);   // 768 f32
    float* db1s  = (float*)(bufU + 9728);   // 256 f32
    float* xyznS = (float*)(bufU + 10240);  // 192 f32
    int*   idxs  = (int*)  (bufU + 10624);  // 64 int

    // stage 0: indices + pos-mlp layer-1 params
    if (t < 64) idxs[t] = knn_idx[G0 * 16 + t];
    dw1s[t] = dw1[t]; dw1s[256 + t] = dw1[256 + t]; dw1s[512 + t] = dw1[512 + t];
    db1s[t] = db1[t];
    __syncthreads();

    // stage 1: centered coords + gather neighbor features
    if (t < 64){
        int G = G0 + (t >> 4); int bb = G >> 10; int p = idxs[t];
        const float* xp = xyz + ((size_t)bb * 4096 + p) * 3;
        const float* nz = nxyz + (size_t)G * 3;
        xyznS[t * 3 + 0] = xp[0] - nz[0];
        xyznS[t * 3 + 1] = xp[1] - nz[1];
        xyznS[t * 3 + 2] = xp[2] - nz[2];
    }
    {
        int r = t >> 2, seg = t & 3;
        int G = G0 + (r >> 4); int bb = G >> 10; int p = idxs[r];
        const uint4* src = (const uint4*)(pts16 + ((size_t)bb * 4096 + p) * 128 + seg * 32);
#pragma unroll
        for (int j = 0; j < 4; j++){
            uint4 v = src[j];
            *(uint4*)(ptsA + swz<4>(r, seg * 32 + j * 8)) = v;
        }
    }
    __syncthreads();

    // stage 2: pos1 = relu(xyzn @ dw1 + db1) -> bufA
    {
        int r = lane;
        int o0 = wave * 64;
        float x = xyznS[r * 3], y = xyznS[r * 3 + 1], z = xyznS[r * 3 + 2];
#pragma unroll
        for (int j = 0; j < 64; j += 4){
            int o = o0 + j;
            f32x4 v;
#pragma unroll
            for (int e = 0; e < 4; e++)
                v[e] = fmaxf(db1s[o + e] + x * dw1s[o + e] + y * dw1s[256 + o + e] + z * dw1s[512 + o + e], 0.f);
            st4(bufA + swz<8>(r, o), v);
        }
    }
    __syncthreads();

    // stage 3: pos2 (P) and K GEMMs
    f32x4 accP[4][4]; ZERO44(accP);
    gemmT<8>(dw2T, bufA, ch0, lane, accP);
#pragma unroll
    for (int mt = 0; mt < 4; mt++){
        f32x4 d2v = *(const f32x4*)(db2 + ch0 + mt * 16 + q * 4);
#pragma unroll
        for (int nt = 0; nt < 4; nt++) accP[mt][nt] += d2v;
    }
    f32x4 accK[4][4]; ZERO44(accK);
    gemmT<4>(wkT, ptsA, ch0, lane, accK);
    __syncthreads();                     // pos1 reads complete

    // stage 4: t = q - k + pos  -> bufA ; then V GEMM
#pragma unroll
    for (int mt = 0; mt < 4; mt++){
        int c = ch0 + mt * 16 + q * 4;
#pragma unroll
        for (int nt = 0; nt < 4; nt++){
            int r = nt * 16 + i;
            f32x4 qv = *(const f32x4*)(qbuf + (size_t)(G0 + nt) * 256 + c);
            f32x4 tv = qv - accK[mt][nt] + accP[mt][nt];
            st4(bufA + swz<8>(r, c), tv);
        }
    }
    f32x4 accV[4][4]; ZERO44(accV);
    gemmT<4>(wvT, ptsA, ch0, lane, accV);
    __syncthreads();                     // t visible; ptsA reads complete

    // stage 5: u = v + pos -> bufU ; att1 GEMM on t
#pragma unroll
    for (int mt = 0; mt < 4; mt++){
        int c = ch0 + mt * 16 + q * 4;
#pragma unroll
        for (int nt = 0; nt < 4; nt++){
            int r = nt * 16 + i;
            f32x4 uv = accV[mt][nt] + accP[mt][nt];
            st4(bufU + swz<8>(r, c), uv);
        }
    }
    f32x4 acc1[4][4]; ZERO44(acc1);
    gemmT<8>(gw1T, bufA, ch0, lane, acc1);
    __syncthreads();                     // t reads complete; u visible

    // stage 6: a1 = relu(. + gb1) -> bufA
#pragma unroll
    for (int mt = 0; mt < 4; mt++){
        int c = ch0 + mt * 16 + q * 4;
        f32x4 g1v = *(const f32x4*)(gb1 + c);
#pragma unroll
        for (int nt = 0; nt < 4; nt++){
            int r = nt * 16 + i;
            f32x4 av = acc1[mt][nt] + g1v;
#pragma unroll
            for (int e = 0; e < 4; e++) av[e] = fmaxf(av[e], 0.f);
            st4(bufA + swz<8>(r, c), av);
        }
    }
    __syncthreads();                     // a1 visible

    // stage 7: att2 GEMM
    f32x4 acc2[4][4]; ZERO44(acc2);
    gemmT<8>(gw2T, bufA, ch0, lane, acc2);
    __syncthreads();                     // a1 reads complete

    // stage 8: e = exp((att + gb2)/16) -> bufA  (values ~1.0, max-sub safely skipped)
#pragma unroll
    for (int mt = 0; mt < 4; mt++){
        int c = ch0 + mt * 16 + q * 4;
        f32x4 g2v = *(const f32x4*)(gb2 + c);
#pragma unroll
        for (int nt = 0; nt < 4; nt++){
            int r = nt * 16 + i;
            f32x4 ev;
#pragma unroll
            for (int e = 0; e < 4; e++) ev[e] = __expf((acc2[mt][nt][e] + g2v[e]) * 0.0625f);
            st4(bufA + swz<8>(r, c), ev);
        }
    }
    __syncthreads();                     // e visible

    // stage 9: softmax-weighted sum over the 16 neighbors of each group
    {
        int g = t >> 6, c4 = (t & 63) * 4;
        f32x4 num; num[0]=0.f;num[1]=0.f;num[2]=0.f;num[3]=0.f;
        f32x4 den = num;
#pragma unroll
        for (int rr = 0; rr < 16; rr++){
            int r = g * 16 + rr;
            f32x4 e4 = ld4(bufA + swz<8>(r, c4));
            f32x4 u4 = ld4(bufU + swz<8>(r, c4));
            num += e4 * u4;
            den += e4;
        }
        f32x4 rv = num / den;
        st4(resY + (size_t)(G0 + g) * 256 + c4, rv);
    }
}

// ---------- kernel 5: z = res @ lw + lb, + channel stats ----------
__global__ __launch_bounds__(256, 2) void z_gemm(const unsigned short* __restrict__ resY,
                                                 const unsigned short* __restrict__ lwT,
                                                 const float* __restrict__ lb,
                                                 float* __restrict__ zbuf,
                                                 float* __restrict__ stats)
{
    int t = threadIdx.x, lane = t & 63, wave = t >> 6;
    int i = lane & 15, q = lane >> 4;
    int row0 = blockIdx.x * 128;
    int ch0 = wave * 64;
    f32x4 acc[4][8];
#pragma unroll
    for (int mt = 0; mt < 4; mt++)
#pragma unroll
        for (int nt = 0; nt < 8; nt++){ acc[mt][nt][0]=0.f;acc[mt][nt][1]=0.f;acc[mt][nt][2]=0.f;acc[mt][nt][3]=0.f; }
#pragma unroll
    for (int kt = 0; kt < 8; kt++){
        int k0 = kt * 32 + q * 8;
        bf16x8 a[4], bb[8];
#pragma unroll
        for (int mt = 0; mt < 4; mt++)
            a[mt] = *(const bf16x8*)(lwT + (size_t)(ch0 + mt * 16 + i) * 256 + k0);
#pragma unroll
        for (int nt = 0; nt < 8; nt++)
            bb[nt] = *(const bf16x8*)(resY + (size_t)(row0 + nt * 16 + i) * 256 + k0);
#pragma unroll
        for (int mt = 0; mt < 4; mt++)
#pragma unroll
            for (int nt = 0; nt < 8; nt++)
                acc[mt][nt] = __builtin_amdgcn_mfma_f32_16x16x32_bf16(a[mt], bb[nt], acc[mt][nt], 0, 0, 0);
    }
    f32x4 s1[4], s2[4];
#pragma unroll
    for (int mt = 0; mt < 4; mt++){ s1[mt][0]=0.f;s1[mt][1]=0.f;s1[mt][2]=0.f;s1[mt][3]=0.f; s2[mt]=s1[mt]; }
#pragma unroll
    for (int mt = 0; mt < 4; mt++){
        int c = ch0 + mt * 16 + q * 4;
        f32x4 lb4 = *(const f32x4*)(lb + c);
#pragma unroll
        for (int nt = 0; nt < 8; nt++){
            int r = row0 + nt * 16 + i;
            f32x4 z = acc[mt][nt] + lb4;
            *(f32x4*)(zbuf + (size_t)r * 256 + c) = z;
            s1[mt] += z;
            s2[mt] += z * z;
        }
    }
    for (int m = 1; m < 16; m <<= 1){
#pragma unroll
        for (int mt = 0; mt < 4; mt++)
#pragma unroll
            for (int e = 0; e < 4; e++){
                s1[mt][e] += __shfl_xor(s1[mt][e], m);
                s2[mt][e] += __shfl_xor(s2[mt][e], m);
            }
    }
    if (i == 0){
#pragma unroll
        for (int mt = 0; mt < 4; mt++){
            int c = ch0 + mt * 16 + q * 4;
#pragma unroll
            for (int e = 0; e < 4; e++){
                atomicAdd(&stats[c + e], s1[mt][e]);
                atomicAdd(&stats[256 + c + e], s2[mt][e]);
            }
        }
    }
}

// ---------- kernel 6: BN (batch stats) + ReLU ----------
__global__ __launch_bounds__(256) void bn_kernel(const float* __restrict__ zbuf,
                                                 const float* __restrict__ stats,
                                                 const float* __restrict__ bn_g,
                                                 const float* __restrict__ bn_b,
                                                 float* __restrict__ out)
{
    int G = blockIdx.x, c = threadIdx.x;
    float mean = stats[c] * (1.f / 8192.f);
    float var = stats[256 + c] * (1.f / 8192.f) - mean * mean;
    float inv = rsqrtf(var + 1e-5f);
    float z = zbuf[(size_t)G * 256 + c];
    float y = bn_g[c] * (z - mean) * inv + bn_b[c];
    out[24576 + (size_t)G * 256 + c] = fmaxf(y, 0.f);
}

__global__ __launch_bounds__(256) void zero_stats(float* __restrict__ stats)
{
    int i = blockIdx.x * 256 + threadIdx.x;
    if (i < 512) stats[i] = 0.f;
}

// ---------- launch ----------
extern "C" void kernel_launch(void* const* d_in, const int* in_sizes, int n_in,
                              void* d_out, int out_size, void* d_ws, size_t ws_size,
                              hipStream_t stream)
{
    const float* xyz    = (const float*)d_in[0];
    const float* points = (const float*)d_in[1];
    const float* wq  = (const float*)d_in[2];
    const float* wk  = (const float*)d_in[3];
    const float* wv  = (const float*)d_in[4];
    const float* dw1 = (const float*)d_in[5];
    const float* db1 = (const float*)d_in[6];
    const float* dw2 = (const float*)d_in[7];
    const float* db2 = (const float*)d_in[8];
    const float* gw1 = (const float*)d_in[9];
    const float* gb1 = (const float*)d_in[10];
    const float* gw2 = (const float*)d_in[11];
    const float* gb2 = (const float*)d_in[12];
    const float* lw  = (const float*)d_in[13];
    const float* lb  = (const float*)d_in[14];
    const float* bn_g = (const float*)d_in[15];
    const float* bn_b = (const float*)d_in[16];
    float* out = (float*)d_out;

    char* ws = (char*)d_ws;
    int*            fps_idx = (int*)(ws + 0);
    int*            knn_idx = (int*)(ws + 32768);
    float*          qbuf    = (float*)(ws + 557056);
    unsigned short* pts16   = (unsigned short*)(ws + 8945664);
    unsigned short* wkT     = (unsigned short*)(ws + 17334272);
    unsigned short* wvT     = (unsigned short*)(ws + 17399808);
    unsigned short* dw2T    = (unsigned short*)(ws + 17465344);
    unsigned short* gw1T    = (unsigned short*)(ws + 17596416);
    unsigned short* gw2T    = (unsigned short*)(ws + 17727488);
    unsigned short* lwT     = (unsigned short*)(ws + 17858560);
    float*          wqT     = (float*)(ws + 17989632);
    unsigned short* resY    = (unsigned short*)(ws + 18120704);
    float*          zbuf    = (float*)(ws + 22315008);
    float*          stats   = (float*)(ws + 30703616);

    prep_weights<<<1408, 256, 0, stream>>>(wq, wk, wv, dw2, gw1, gw2, lw,
                                           wqT, wkT, wvT, dw2T, gw1T, gw2T, lwT);
    cvt_points<<<4096, 256, 0, stream>>>(points, pts16);
    fps_kernel<<<8, 256, 0, stream>>>(xyz, out, fps_idx);
    knn_kernel<<<8192, 256, 0, stream>>>(xyz, out, knn_idx);
    q_kernel<<<1024, 256, 0, stream>>>(points, wqT, fps_idx, qbuf);
    fused_attn<<<2048, 256, 0, stream>>>(pts16, xyz, out, knn_idx, qbuf,
                                         wkT, wvT, dw2T, gw1T, gw2T,
                                         dw1, db1, db2, gb1, gb2, resY);
    zero_stats<<<2, 256, 0, stream>>>(stats);
    z_gemm<<<64, 256, 0, stream>>>(resY, lwT, lb, zbuf, stats);
    bn_kernel<<<8192, 256, 0, stream>>>(zbuf, stats, bn_g, bn_b, out);
}

// Round 3
// 1063.089 us; speedup vs baseline: 1.4110x; 1.4110x over previous
//
#include <hip/hip_runtime.h>

typedef unsigned long long ull;
typedef __attribute__((ext_vector_type(8))) short bf16x8;
typedef __attribute__((ext_vector_type(4))) float f32x4;

// ---------- helpers ----------
__device__ __forceinline__ unsigned short bf16b(float x){
    unsigned u = __float_as_uint(x);
    unsigned r = (u + 0x7FFFu + ((u >> 16) & 1u)) >> 16;
    return (unsigned short)r;
}
__device__ __forceinline__ float b2f(unsigned short u){
    return __uint_as_float(((unsigned)u) << 16);
}
__device__ __forceinline__ void st4(unsigned short* p, f32x4 v){
    ull pk = (ull)bf16b(v[0]) | (((ull)bf16b(v[1])) << 16)
           | (((ull)bf16b(v[2])) << 32) | (((ull)bf16b(v[3])) << 48);
    *(ull*)p = pk;
}
__device__ __forceinline__ f32x4 ld4(const unsigned short* p){
    ull pk = *(const ull*)p;
    f32x4 v;
    v[0] = b2f((unsigned short)pk);
    v[1] = b2f((unsigned short)(pk >> 16));
    v[2] = b2f((unsigned short)(pk >> 32));
    v[3] = b2f((unsigned short)(pk >> 48));
    return v;
}

// u64 DPP reductions (max for FPS, min for KNN). All-lane valid, row_mask 0xF safe.
#define DPPMAX(k, ctrl) do { \
    unsigned _lo = (unsigned)(k), _hi = (unsigned)((k) >> 32); \
    unsigned _l2 = (unsigned)__builtin_amdgcn_update_dpp((int)_lo, (int)_lo, (ctrl), 0xF, 0xF, false); \
    unsigned _h2 = (unsigned)__builtin_amdgcn_update_dpp((int)_hi, (int)_hi, (ctrl), 0xF, 0xF, false); \
    ull _k2 = (((ull)_h2) << 32) | _l2; \
    if (_k2 > (k)) (k) = _k2; \
} while (0)
#define DPPMIN(k, ctrl) do { \
    unsigned _lo = (unsigned)(k), _hi = (unsigned)((k) >> 32); \
    unsigned _l2 = (unsigned)__builtin_amdgcn_update_dpp((int)_lo, (int)_lo, (ctrl), 0xF, 0xF, false); \
    unsigned _h2 = (unsigned)__builtin_amdgcn_update_dpp((int)_hi, (int)_hi, (ctrl), 0xF, 0xF, false); \
    ull _k2 = (((ull)_h2) << 32) | _l2; \
    if (_k2 < (k)) (k) = _k2; \
} while (0)
// ctrl codes: quad_perm(1,0,3,2)=0xB1, quad_perm(2,3,0,1)=0x4E,
// row_half_mirror=0x141, row_mirror=0x140, row_bcast15=0x142, row_bcast31=0x143

// XOR-swizzled LDS layout for row-major [rows][K*?] bf16 tiles, K-width = KT*32.
template<int KT>
__device__ __forceinline__ int swz(int r, int c){
    return r * (KT * 32) + ((((c >> 3) + r) & (KT * 4 - 1)) << 3) + (c & 7);
}

// D[ch][row] += W^T[ch][k] * data[row][k]; A from global (row-major [ch][K]),
// B from swizzled LDS (row-major [row][K]). Wave covers 64 ch (mt 0..3) x 64 rows (nt 0..3).
template<int KT>
__device__ __forceinline__ void gemmT(const unsigned short* __restrict__ Wt,
                                      const unsigned short* __restrict__ Blds,
                                      int ch0, int lane, f32x4 acc[4][4])
{
    int i = lane & 15, q = lane >> 4;
#pragma unroll
    for (int kt = 0; kt < KT; kt++){
        int k0 = kt * 32 + q * 8;
        bf16x8 bfr[4], afr[4];
#pragma unroll
        for (int nt = 0; nt < 4; nt++)
            bfr[nt] = *(const bf16x8*)(Blds + swz<KT>(nt * 16 + i, k0));
#pragma unroll
        for (int mt = 0; mt < 4; mt++)
            afr[mt] = *(const bf16x8*)(Wt + (size_t)(ch0 + mt * 16 + i) * (KT * 32) + k0);
#pragma unroll
        for (int mt = 0; mt < 4; mt++)
#pragma unroll
            for (int nt = 0; nt < 4; nt++)
                acc[mt][nt] = __builtin_amdgcn_mfma_f32_16x16x32_bf16(afr[mt], bfr[nt], acc[mt][nt], 0, 0, 0);
    }
}

#define ZERO44(A) do { _Pragma("unroll") for (int _m = 0; _m < 4; _m++) \
    { _Pragma("unroll") for (int _n = 0; _n < 4; _n++) { A[_m][_n][0]=0.f;A[_m][_n][1]=0.f;A[_m][_n][2]=0.f;A[_m][_n][3]=0.f; } } } while(0)

// ---------- kernel 1: fps_mega ----------
// blocks 0..7: farthest point sampling (exact, numpy-faithful), 512 thr = 2 waves/SIMD.
// blocks 8..:  independent prep work (weight transpose/bf16, points->bf16, stats zero)
//              running concurrently on the other 248 CUs while FPS runs.
//
// FPS per step: inline u64 key (dist_bits<<32 | ~p) tournament per lane (index
// recovery is free), 6-stage DPP u64 wave-max -> lane63 writes parity slot,
// barrier, lane-parallel slot read (lane l reads slot[l&7]) + 3-stage DPP u64
// max over 8-groups -> every lane has global winner. Global stores out of loop.
__global__ __launch_bounds__(512) void fps_mega(
    const float* __restrict__ xyz, float* __restrict__ nxyz_out, int* __restrict__ fps_idx,
    const float* __restrict__ pts, unsigned short* __restrict__ pts16,
    const float* __restrict__ wq, const float* __restrict__ wk, const float* __restrict__ wv,
    const float* __restrict__ dw2, const float* __restrict__ gw1, const float* __restrict__ gw2,
    const float* __restrict__ lw,
    float* __restrict__ wqT, unsigned short* __restrict__ wkT, unsigned short* __restrict__ wvT,
    unsigned short* __restrict__ dw2T, unsigned short* __restrict__ gw1T,
    unsigned short* __restrict__ gw2T, unsigned short* __restrict__ lwT,
    float* __restrict__ stats)
{
    __shared__ float sx[4096], sy[4096], sz[4096];
    __shared__ int farS[1024];
    __shared__ ull slotK[2][8];

    int blk = blockIdx.x;
    int t = threadIdx.x;

    if (blk >= 8){
        int aux = blk - 8;
        if (aux < 704){
            // prep_weights: same index chain as before, 512 thr/block
            if (aux == 0) stats[t] = 0.f;
            int i = aux * 512 + t;
            if (i < 32768){ int n = i >> 7, k = i & 127; wqT[i] = wq[k * 256 + n]; return; } i -= 32768;
            if (i < 32768){ int n = i >> 7, k = i & 127; wkT[i] = bf16b(wk[k * 256 + n]); return; } i -= 32768;
            if (i < 32768){ int n = i >> 7, k = i & 127; wvT[i] = bf16b(wv[k * 256 + n]); return; } i -= 32768;
            if (i < 65536){ int n = i >> 8, k = i & 255; dw2T[i] = bf16b(dw2[k * 256 + n]); return; } i -= 65536;
            if (i < 65536){ int n = i >> 8, k = i & 255; gw1T[i] = bf16b(gw1[k * 256 + n]); return; } i -= 65536;
            if (i < 65536){ int n = i >> 8, k = i & 255; gw2T[i] = bf16b(gw2[k * 256 + n]); return; } i -= 65536;
            if (i < 65536){ int n = i >> 8, k = i & 255; lwT[i]  = bf16b(lw[k * 256 + n]); return; }
            return;
        }
        // cvt_points: 2048 blocks x 512 thr x 4 elems = 8*4096*128
        int i = ((aux - 704) * 512 + t) * 4;
        f32x4 v = *(const f32x4*)(pts + i);
        ull pk = (ull)bf16b(v[0]) | (((ull)bf16b(v[1])) << 16)
               | (((ull)bf16b(v[2])) << 32) | (((ull)bf16b(v[3])) << 48);
        *(ull*)(pts16 + i) = pk;
        return;
    }

    // ---- FPS (blocks 0..7) ----
    int b = blk;
    int lane = t & 63, wvi = t >> 6;
    for (int p = t; p < 4096; p += 512){
        const float* s = xyz + ((size_t)b * 4096 + p) * 3;
        sx[p] = s[0]; sy[p] = s[1]; sz[p] = s[2];
    }
    __syncthreads();
    float px[8], py[8], pz[8], dist[8];
    unsigned nplo[8];
#pragma unroll
    for (int j = 0; j < 8; j++){
        int p = t + (j << 9);
        px[j] = sx[p]; py[j] = sy[p]; pz[j] = sz[p];
        dist[j] = 1e10f;
        nplo[j] = ~(unsigned)p;
    }
    int far = 0;
    float cx = sx[0], cy = sy[0], cz = sz[0];
    int par = 0;
    for (int s = 0; s < 1024; s++){
        if (t == 0) farS[s] = far;
        ull lb = 0;
#pragma unroll
        for (int j = 0; j < 8; j++){
            float dx = __fsub_rn(px[j], cx);
            float dy = __fsub_rn(py[j], cy);
            float dz = __fsub_rn(pz[j], cz);
            float d = __fadd_rn(__fadd_rn(__fmul_rn(dx, dx), __fmul_rn(dy, dy)), __fmul_rn(dz, dz));
            float nd = fminf(dist[j], d);
            dist[j] = nd;
            ull k2 = (((ull)__float_as_uint(nd)) << 32) | nplo[j];
            if (k2 > lb) lb = k2;
        }
        // wave max (6 stages; lane63 holds the result)
        DPPMAX(lb, 0xB1); DPPMAX(lb, 0x4E); DPPMAX(lb, 0x141);
        DPPMAX(lb, 0x140); DPPMAX(lb, 0x142); DPPMAX(lb, 0x143);
        if (lane == 63) slotK[par][wvi] = lb;
        __syncthreads();
        // cross-wave: lane l reads slot[l&7]; 3-stage DPP max over each 8-group
        ull k = slotK[par][lane & 7];
        DPPMAX(k, 0xB1); DPPMAX(k, 0x4E); DPPMAX(k, 0x141);
        far = (int)(~(unsigned)k);
        cx = sx[far]; cy = sy[far]; cz = sz[far];
        par ^= 1;
    }
    // write outputs once (off the serial critical path)
    float* outp = nxyz_out + (size_t)b * 3072;
    for (int s2 = t; s2 < 1024; s2 += 512){
        int f = farS[s2];
        fps_idx[b * 1024 + s2] = f;
        outp[s2 * 3 + 0] = sx[f];
        outp[s2 * 3 + 1] = sy[f];
        outp[s2 * 3 + 2] = sz[f];
    }
}

// ---------- kernel 2: KNN (16 smallest d2 per sampled point) ----------
__global__ __launch_bounds__(256) void knn_kernel(const float* __restrict__ xyz,
                                                  const float* __restrict__ nxyz,
                                                  int* __restrict__ knn_idx)
{
    __shared__ float d2s[4096];
    __shared__ ull kslot[4];
    int G = blockIdx.x; int b = G >> 10;
    int t = threadIdx.x, lane = t & 63, wvi = t >> 6;
    float qx = nxyz[(size_t)G * 3], qy = nxyz[(size_t)G * 3 + 1], qz = nxyz[(size_t)G * 3 + 2];
    float qq = qx * qx + qy * qy + qz * qz;
    for (int j = 0; j < 16; j++){
        int p = t + (j << 8);
        const float* s = xyz + ((size_t)b * 4096 + p) * 3;
        float x = s[0], y = s[1], z = s[2];
        d2s[p] = qq - 2.f * (qx * x + qy * y + qz * z) + (x * x + y * y + z * z);
    }
    __syncthreads();
    for (int r = 0; r < 16; r++){
        ull best = ~0ull;
#pragma unroll
        for (int j = 0; j < 16; j++){
            int p = t + (j << 8);
            unsigned bb = __float_as_uint(d2s[p]);
            bb = (bb & 0x80000000u) ? ~bb : (bb | 0x80000000u);
            ull key = (((ull)bb) << 32) | (unsigned)p;
            if (key < best) best = key;
        }
        DPPMIN(best, 0xB1); DPPMIN(best, 0x4E); DPPMIN(best, 0x141);
        DPPMIN(best, 0x140); DPPMIN(best, 0x142); DPPMIN(best, 0x143);
        if (lane == 63) kslot[wvi] = best;
        __syncthreads();
        if (t == 0){
            ull bk = kslot[0];
            for (int w = 1; w < 4; w++) if (kslot[w] < bk) bk = kslot[w];
            int p = (int)(unsigned)bk;
            knn_idx[(size_t)G * 16 + r] = p;
            d2s[p] = 3.0e38f;
        }
        __syncthreads();
    }
}

// ---------- kernel 3: q = sampled_points @ wq (f32) ----------
__global__ __launch_bounds__(256) void q_kernel(const float* __restrict__ points,
                                                const float* __restrict__ wqT,
                                                const int* __restrict__ fps_idx,
                                                float* __restrict__ qbuf)
{
    __shared__ float sp[8][128];
    int t = threadIdx.x;
    int g0 = blockIdx.x * 8;
    {
        int r = t >> 5, c = (t & 31) * 4;
        int G = g0 + r; int b = G >> 10; int p = fps_idx[G];
        const f32x4 v = *(const f32x4*)(points + ((size_t)b * 4096 + p) * 128 + c);
        *(f32x4*)&sp[r][c] = v;
    }
    __syncthreads();
    float acc[8] = {0.f,0.f,0.f,0.f,0.f,0.f,0.f,0.f};
    const float* wr = wqT + t * 128;
    for (int k = 0; k < 128; k += 4){
        f32x4 w = *(const f32x4*)(wr + k);
#pragma unroll
        for (int r = 0; r < 8; r++)
            acc[r] += w[0]*sp[r][k] + w[1]*sp[r][k+1] + w[2]*sp[r][k+2] + w[3]*sp[r][k+3];
    }
#pragma unroll
    for (int r = 0; r < 8; r++) qbuf[(size_t)(g0 + r) * 256 + t] = acc[r];
}

// ---------- kernel 4: fused attention stack (4 groups / block) ----------
__global__ __launch_bounds__(256, 2) void fused_attn(
    const unsigned short* __restrict__ pts16,
    const float* __restrict__ xyz, const float* __restrict__ nxyz,
    const int* __restrict__ knn_idx, const float* __restrict__ qbuf,
    const unsigned short* __restrict__ wkT, const unsigned short* __restrict__ wvT,
    const unsigned short* __restrict__ dw2T, const unsigned short* __restrict__ gw1T,
    const unsigned short* __restrict__ gw2T,
    const float* __restrict__ dw1, const float* __restrict__ db1,
    const float* __restrict__ db2, const float* __restrict__ gb1, const float* __restrict__ gb2,
    unsigned short* __restrict__ resY)
{
    __shared__ unsigned short bufA[16384];  // pos1 -> t -> a1 -> e   [64][256] swz<8>
    __shared__ unsigned short bufU[16384];  // ptsA(swz<4>) -> u(swz<8>)
    int t = threadIdx.x, lane = t & 63, wave = t >> 6;
    int i = lane & 15, q = lane >> 4;
    int G0 = blockIdx.x * 4;
    int ch0 = wave * 64;
    unsigned short* ptsA = bufU;
    float* dw1s  = (float*)(bufU + 8192);   // 768 f32
    float* db1s  = (float*)(bufU + 9728);   // 256 f32
    float* xyznS = (float*)(bufU + 10240);  // 192 f32
    int*   idxs  = (int*)  (bufU + 10624);  // 64 int

    // stage 0: indices + pos-mlp layer-1 params
    if (t < 64) idxs[t] = knn_idx[G0 * 16 + t];
    dw1s[t] = dw1[t]; dw1s[256 + t] = dw1[256 + t]; dw1s[512 + t] = dw1[512 + t];
    db1s[t] = db1[t];
    __syncthreads();

    // stage 1: centered coords + gather neighbor features
    if (t < 64){
        int G = G0 + (t >> 4); int bb = G >> 10; int p = idxs[t];
        const float* xp = xyz + ((size_t)bb * 4096 + p) * 3;
        const float* nz = nxyz + (size_t)G * 3;
        xyznS[t * 3 + 0] = xp[0] - nz[0];
        xyznS[t * 3 + 1] = xp[1] - nz[1];
        xyznS[t * 3 + 2] = xp[2] - nz[2];
    }
    {
        int r = t >> 2, seg = t & 3;
        int G = G0 + (r >> 4); int bb = G >> 10; int p = idxs[r];
        const uint4* src = (const uint4*)(pts16 + ((size_t)bb * 4096 + p) * 128 + seg * 32);
#pragma unroll
        for (int j = 0; j < 4; j++){
            uint4 v = src[j];
            *(uint4*)(ptsA + swz<4>(r, seg * 32 + j * 8)) = v;
        }
    }
    __syncthreads();

    // stage 2: pos1 = relu(xyzn @ dw1 + db1) -> bufA
    {
        int r = lane;
        int o0 = wave * 64;
        float x = xyznS[r * 3], y = xyznS[r * 3 + 1], z = xyznS[r * 3 + 2];
#pragma unroll
        for (int j = 0; j < 64; j += 4){
            int o = o0 + j;
            f32x4 v;
#pragma unroll
            for (int e = 0; e < 4; e++)
                v[e] = fmaxf(db1s[o + e] + x * dw1s[o + e] + y * dw1s[256 + o + e] + z * dw1s[512 + o + e], 0.f);
            st4(bufA + swz<8>(r, o), v);
        }
    }
    __syncthreads();

    // stage 3: pos2 (P) and K GEMMs
    f32x4 accP[4][4]; ZERO44(accP);
    gemmT<8>(dw2T, bufA, ch0, lane, accP);
#pragma unroll
    for (int mt = 0; mt < 4; mt++){
        f32x4 d2v = *(const f32x4*)(db2 + ch0 + mt * 16 + q * 4);
#pragma unroll
        for (int nt = 0; nt < 4; nt++) accP[mt][nt] += d2v;
    }
    f32x4 accK[4][4]; ZERO44(accK);
    gemmT<4>(wkT, ptsA, ch0, lane, accK);
    __syncthreads();                     // pos1 reads complete

    // stage 4: t = q - k + pos  -> bufA ; then V GEMM
#pragma unroll
    for (int mt = 0; mt < 4; mt++){
        int c = ch0 + mt * 16 + q * 4;
#pragma unroll
        for (int nt = 0; nt < 4; nt++){
            int r = nt * 16 + i;
            f32x4 qv = *(const f32x4*)(qbuf + (size_t)(G0 + nt) * 256 + c);
            f32x4 tv = qv - accK[mt][nt] + accP[mt][nt];
            st4(bufA + swz<8>(r, c), tv);
        }
    }
    f32x4 accV[4][4]; ZERO44(accV);
    gemmT<4>(wvT, ptsA, ch0, lane, accV);
    __syncthreads();                     // t visible; ptsA reads complete

    // stage 5: u = v + pos -> bufU ; att1 GEMM on t
#pragma unroll
    for (int mt = 0; mt < 4; mt++){
        int c = ch0 + mt * 16 + q * 4;
#pragma unroll
        for (int nt = 0; nt < 4; nt++){
            int r = nt * 16 + i;
            f32x4 uv = accV[mt][nt] + accP[mt][nt];
            st4(bufU + swz<8>(r, c), uv);
        }
    }
    f32x4 acc1[4][4]; ZERO44(acc1);
    gemmT<8>(gw1T, bufA, ch0, lane, acc1);
    __syncthreads();                     // t reads complete; u visible

    // stage 6: a1 = relu(. + gb1) -> bufA
#pragma unroll
    for (int mt = 0; mt < 4; mt++){
        int c = ch0 + mt * 16 + q * 4;
        f32x4 g1v = *(const f32x4*)(gb1 + c);
#pragma unroll
        for (int nt = 0; nt < 4; nt++){
            int r = nt * 16 + i;
            f32x4 av = acc1[mt][nt] + g1v;
#pragma unroll
            for (int e = 0; e < 4; e++) av[e] = fmaxf(av[e], 0.f);
            st4(bufA + swz<8>(r, c), av);
        }
    }
    __syncthreads();                     // a1 visible

    // stage 7: att2 GEMM
    f32x4 acc2[4][4]; ZERO44(acc2);
    gemmT<8>(gw2T, bufA, ch0, lane, acc2);
    __syncthreads();                     // a1 reads complete

    // stage 8: e = exp((att + gb2)/16) -> bufA  (values ~1.0, max-sub safely skipped)
#pragma unroll
    for (int mt = 0; mt < 4; mt++){
        int c = ch0 + mt * 16 + q * 4;
        f32x4 g2v = *(const f32x4*)(gb2 + c);
#pragma unroll
        for (int nt = 0; nt < 4; nt++){
            int r = nt * 16 + i;
            f32x4 ev;
#pragma unroll
            for (int e = 0; e < 4; e++) ev[e] = __expf((acc2[mt][nt][e] + g2v[e]) * 0.0625f);
            st4(bufA + swz<8>(r, c), ev);
        }
    }
    __syncthreads();                     // e visible

    // stage 9: softmax-weighted sum over the 16 neighbors of each group
    {
        int g = t >> 6, c4 = (t & 63) * 4;
        f32x4 num; num[0]=0.f;num[1]=0.f;num[2]=0.f;num[3]=0.f;
        f32x4 den = num;
#pragma unroll
        for (int rr = 0; rr < 16; rr++){
            int r = g * 16 + rr;
            f32x4 e4 = ld4(bufA + swz<8>(r, c4));
            f32x4 u4 = ld4(bufU + swz<8>(r, c4));
            num += e4 * u4;
            den += e4;
        }
        f32x4 rv = num / den;
        st4(resY + (size_t)(G0 + g) * 256 + c4, rv);
    }
}

// ---------- kernel 5: z = res @ lw + lb, + channel stats ----------
__global__ __launch_bounds__(256, 2) void z_gemm(const unsigned short* __restrict__ resY,
                                                 const unsigned short* __restrict__ lwT,
                                                 const float* __restrict__ lb,
                                                 float* __restrict__ zbuf,
                                                 float* __restrict__ stats)
{
    int t = threadIdx.x, lane = t & 63, wave = t >> 6;
    int i = lane & 15, q = lane >> 4;
    int row0 = blockIdx.x * 128;
    int ch0 = wave * 64;
    f32x4 acc[4][8];
#pragma unroll
    for (int mt = 0; mt < 4; mt++)
#pragma unroll
        for (int nt = 0; nt < 8; nt++){ acc[mt][nt][0]=0.f;acc[mt][nt][1]=0.f;acc[mt][nt][2]=0.f;acc[mt][nt][3]=0.f; }
#pragma unroll
    for (int kt = 0; kt < 8; kt++){
        int k0 = kt * 32 + q * 8;
        bf16x8 a[4], bb[8];
#pragma unroll
        for (int mt = 0; mt < 4; mt++)
            a[mt] = *(const bf16x8*)(lwT + (size_t)(ch0 + mt * 16 + i) * 256 + k0);
#pragma unroll
        for (int nt = 0; nt < 8; nt++)
            bb[nt] = *(const bf16x8*)(resY + (size_t)(row0 + nt * 16 + i) * 256 + k0);
#pragma unroll
        for (int mt = 0; mt < 4; mt++)
#pragma unroll
            for (int nt = 0; nt < 8; nt++)
                acc[mt][nt] = __builtin_amdgcn_mfma_f32_16x16x32_bf16(a[mt], bb[nt], acc[mt][nt], 0, 0, 0);
    }
    f32x4 s1[4], s2[4];
#pragma unroll
    for (int mt = 0; mt < 4; mt++){ s1[mt][0]=0.f;s1[mt][1]=0.f;s1[mt][2]=0.f;s1[mt][3]=0.f; s2[mt]=s1[mt]; }
#pragma unroll
    for (int mt = 0; mt < 4; mt++){
        int c = ch0 + mt * 16 + q * 4;
        f32x4 lb4 = *(const f32x4*)(lb + c);
#pragma unroll
        for (int nt = 0; nt < 8; nt++){
            int r = row0 + nt * 16 + i;
            f32x4 z = acc[mt][nt] + lb4;
            *(f32x4*)(zbuf + (size_t)r * 256 + c) = z;
            s1[mt] += z;
            s2[mt] += z * z;
        }
    }
    for (int m = 1; m < 16; m <<= 1){
#pragma unroll
        for (int mt = 0; mt < 4; mt++)
#pragma unroll
            for (int e = 0; e < 4; e++){
                s1[mt][e] += __shfl_xor(s1[mt][e], m);
                s2[mt][e] += __shfl_xor(s2[mt][e], m);
            }
    }
    if (i == 0){
#pragma unroll
        for (int mt = 0; mt < 4; mt++){
            int c = ch0 + mt * 16 + q * 4;
#pragma unroll
            for (int e = 0; e < 4; e++){
                atomicAdd(&stats[c + e], s1[mt][e]);
                atomicAdd(&stats[256 + c + e], s2[mt][e]);
            }
        }
    }
}

// ---------- kernel 6: BN (batch stats) + ReLU ----------
__global__ __launch_bounds__(256) void bn_kernel(const float* __restrict__ zbuf,
                                                 const float* __restrict__ stats,
                                                 const float* __restrict__ bn_g,
                                                 const float* __restrict__ bn_b,
                                                 float* __restrict__ out)
{
    int G = blockIdx.x, c = threadIdx.x;
    float mean = stats[c] * (1.f / 8192.f);
    float var = stats[256 + c] * (1.f / 8192.f) - mean * mean;
    float inv = rsqrtf(var + 1e-5f);
    float z = zbuf[(size_t)G * 256 + c];
    float y = bn_g[c] * (z - mean) * inv + bn_b[c];
    out[24576 + (size_t)G * 256 + c] = fmaxf(y, 0.f);
}

// ---------- launch ----------
extern "C" void kernel_launch(void* const* d_in, const int* in_sizes, int n_in,
                              void* d_out, int out_size, void* d_ws, size_t ws_size,
                              hipStream_t stream)
{
    const float* xyz    = (const float*)d_in[0];
    const float* points = (const float*)d_in[1];
    const float* wq  = (const float*)d_in[2];
    const float* wk  = (const float*)d_in[3];
    const float* wv  = (const float*)d_in[4];
    const float* dw1 = (const float*)d_in[5];
    const float* db1 = (const float*)d_in[6];
    const float* dw2 = (const float*)d_in[7];
    const float* db2 = (const float*)d_in[8];
    const float* gw1 = (const float*)d_in[9];
    const float* gb1 = (const float*)d_in[10];
    const float* gw2 = (const float*)d_in[11];
    const float* gb2 = (const float*)d_in[12];
    const float* lw  = (const float*)d_in[13];
    const float* lb  = (const float*)d_in[14];
    const float* bn_g = (const float*)d_in[15];
    const float* bn_b = (const float*)d_in[16];
    float* out = (float*)d_out;

    char* ws = (char*)d_ws;
    int*            fps_idx = (int*)(ws + 0);
    int*            knn_idx = (int*)(ws + 32768);
    float*          qbuf    = (float*)(ws + 557056);
    unsigned short* pts16   = (unsigned short*)(ws + 8945664);
    unsigned short* wkT     = (unsigned short*)(ws + 17334272);
    unsigned short* wvT     = (unsigned short*)(ws + 17399808);
    unsigned short* dw2T    = (unsigned short*)(ws + 17465344);
    unsigned short* gw1T    = (unsigned short*)(ws + 17596416);
    unsigned short* gw2T    = (unsigned short*)(ws + 17727488);
    unsigned short* lwT     = (unsigned short*)(ws + 17858560);
    float*          wqT     = (float*)(ws + 17989632);
    unsigned short* resY    = (unsigned short*)(ws + 18120704);
    float*          zbuf    = (float*)(ws + 22315008);
    float*          stats   = (float*)(ws + 30703616);

    // blocks: 8 FPS + 704 prep (incl stats zero) + 2048 cvt = 2760
    fps_mega<<<2760, 512, 0, stream>>>(xyz, out, fps_idx, points, pts16,
                                       wq, wk, wv, dw2, gw1, gw2, lw,
                                       wqT, wkT, wvT, dw2T, gw1T, gw2T, lwT, stats);
    knn_kernel<<<8192, 256, 0, stream>>>(xyz, out, knn_idx);
    q_kernel<<<1024, 256, 0, stream>>>(points, wqT, fps_idx, qbuf);
    fused_attn<<<2048, 256, 0, stream>>>(pts16, xyz, out, knn_idx, qbuf,
                                         wkT, wvT, dw2T, gw1T, gw2T,
                                         dw1, db1, db2, gb1, gb2, resY);
    z_gemm<<<64, 256, 0, stream>>>(resY, lwT, lb, zbuf, stats);
    bn_kernel<<<8192, 256, 0, stream>>>(zbuf, stats, bn_g, bn_b, out);
}

// Round 4
// 1051.413 us; speedup vs baseline: 1.4267x; 1.0111x over previous
//
#include <hip/hip_runtime.h>

typedef unsigned long long ull;
typedef __attribute__((ext_vector_type(8))) short bf16x8;
typedef __attribute__((ext_vector_type(4))) float f32x4;

// ---------- helpers ----------
__device__ __forceinline__ unsigned short bf16b(float x){
    unsigned u = __float_as_uint(x);
    unsigned r = (u + 0x7FFFu + ((u >> 16) & 1u)) >> 16;
    return (unsigned short)r;
}
__device__ __forceinline__ float b2f(unsigned short u){
    return __uint_as_float(((unsigned)u) << 16);
}
__device__ __forceinline__ void st4(unsigned short* p, f32x4 v){
    ull pk = (ull)bf16b(v[0]) | (((ull)bf16b(v[1])) << 16)
           | (((ull)bf16b(v[2])) << 32) | (((ull)bf16b(v[3])) << 48);
    *(ull*)p = pk;
}
__device__ __forceinline__ f32x4 ld4(const unsigned short* p){
    ull pk = *(const ull*)p;
    f32x4 v;
    v[0] = b2f((unsigned short)pk);
    v[1] = b2f((unsigned short)(pk >> 16));
    v[2] = b2f((unsigned short)(pk >> 32));
    v[3] = b2f((unsigned short)(pk >> 48));
    return v;
}

// u64 DPP reductions (max for FPS, min for KNN). All-lane valid, row_mask 0xF safe.
#define DPPMAX(k, ctrl) do { \
    unsigned _lo = (unsigned)(k), _hi = (unsigned)((k) >> 32); \
    unsigned _l2 = (unsigned)__builtin_amdgcn_update_dpp((int)_lo, (int)_lo, (ctrl), 0xF, 0xF, false); \
    unsigned _h2 = (unsigned)__builtin_amdgcn_update_dpp((int)_hi, (int)_hi, (ctrl), 0xF, 0xF, false); \
    ull _k2 = (((ull)_h2) << 32) | _l2; \
    if (_k2 > (k)) (k) = _k2; \
} while (0)
#define DPPMIN(k, ctrl) do { \
    unsigned _lo = (unsigned)(k), _hi = (unsigned)((k) >> 32); \
    unsigned _l2 = (unsigned)__builtin_amdgcn_update_dpp((int)_lo, (int)_lo, (ctrl), 0xF, 0xF, false); \
    unsigned _h2 = (unsigned)__builtin_amdgcn_update_dpp((int)_hi, (int)_hi, (ctrl), 0xF, 0xF, false); \
    ull _k2 = (((ull)_h2) << 32) | _l2; \
    if (_k2 < (k)) (k) = _k2; \
} while (0)
// ctrl codes: quad_perm(1,0,3,2)=0xB1, quad_perm(2,3,0,1)=0x4E,
// row_half_mirror=0x141, row_mirror=0x140, row_bcast15=0x142, row_bcast31=0x143

// XOR-swizzled LDS layout for row-major [rows][K*?] bf16 tiles, K-width = KT*32.
template<int KT>
__device__ __forceinline__ int swz(int r, int c){
    return r * (KT * 32) + ((((c >> 3) + r) & (KT * 4 - 1)) << 3) + (c & 7);
}

// D[ch][row] += W^T[ch][k] * data[row][k]; A from global (row-major [ch][K]),
// B from swizzled LDS (row-major [row][K]). Wave covers 64 ch (mt 0..3) x 64 rows (nt 0..3).
template<int KT>
__device__ __forceinline__ void gemmT(const unsigned short* __restrict__ Wt,
                                      const unsigned short* __restrict__ Blds,
                                      int ch0, int lane, f32x4 acc[4][4])
{
    int i = lane & 15, q = lane >> 4;
#pragma unroll
    for (int kt = 0; kt < KT; kt++){
        int k0 = kt * 32 + q * 8;
        bf16x8 bfr[4], afr[4];
#pragma unroll
        for (int nt = 0; nt < 4; nt++)
            bfr[nt] = *(const bf16x8*)(Blds + swz<KT>(nt * 16 + i, k0));
#pragma unroll
        for (int mt = 0; mt < 4; mt++)
            afr[mt] = *(const bf16x8*)(Wt + (size_t)(ch0 + mt * 16 + i) * (KT * 32) + k0);
#pragma unroll
        for (int mt = 0; mt < 4; mt++)
#pragma unroll
            for (int nt = 0; nt < 4; nt++)
                acc[mt][nt] = __builtin_amdgcn_mfma_f32_16x16x32_bf16(afr[mt], bfr[nt], acc[mt][nt], 0, 0, 0);
    }
}

#define ZERO44(A) do { _Pragma("unroll") for (int _m = 0; _m < 4; _m++) \
    { _Pragma("unroll") for (int _n = 0; _n < 4; _n++) { A[_m][_n][0]=0.f;A[_m][_n][1]=0.f;A[_m][_n][2]=0.f;A[_m][_n][3]=0.f; } } } while(0)

// ---------- kernel 1: fps_mega ----------
// blocks 0..7: farthest point sampling (exact, numpy-faithful), 512 thr = 2 waves/SIMD.
// blocks 8..:  independent prep work (weight transpose/bf16, points->bf16, stats zero)
//              running concurrently on the other 248 CUs while FPS runs.
//
// __launch_bounds__(512, 2): only 8 FPS blocks exist -> occupancy is irrelevant;
// allow up to 256 VGPRs so the 40-value per-lane point cache (px/py/pz/dist/nplo)
// actually lives in registers. The empty asm pins make the loaded values opaque so
// the compiler cannot rematerialize them from LDS inside the 1024-step loop
// (VGPR_Count=40 + per-active-CU VALUBusy 77% showed it was re-reading LDS every step).
__global__ __launch_bounds__(512, 2) void fps_mega(
    const float* __restrict__ xyz, float* __restrict__ nxyz_out, int* __restrict__ fps_idx,
    const float* __restrict__ pts, unsigned short* __restrict__ pts16,
    const float* __restrict__ wq, const float* __restrict__ wk, const float* __restrict__ wv,
    const float* __restrict__ dw2, const float* __restrict__ gw1, const float* __restrict__ gw2,
    const float* __restrict__ lw,
    float* __restrict__ wqT, unsigned short* __restrict__ wkT, unsigned short* __restrict__ wvT,
    unsigned short* __restrict__ dw2T, unsigned short* __restrict__ gw1T,
    unsigned short* __restrict__ gw2T, unsigned short* __restrict__ lwT,
    float* __restrict__ stats)
{
    __shared__ float sx[4096], sy[4096], sz[4096];
    __shared__ int farS[1024];
    __shared__ ull slotK[2][8];

    int blk = blockIdx.x;
    int t = threadIdx.x;

    if (blk >= 8){
        int aux = blk - 8;
        if (aux < 704){
            // prep_weights: same index chain as before, 512 thr/block
            if (aux == 0) stats[t] = 0.f;
            int i = aux * 512 + t;
            if (i < 32768){ int n = i >> 7, k = i & 127; wqT[i] = wq[k * 256 + n]; return; } i -= 32768;
            if (i < 32768){ int n = i >> 7, k = i & 127; wkT[i] = bf16b(wk[k * 256 + n]); return; } i -= 32768;
            if (i < 32768){ int n = i >> 7, k = i & 127; wvT[i] = bf16b(wv[k * 256 + n]); return; } i -= 32768;
            if (i < 65536){ int n = i >> 8, k = i & 255; dw2T[i] = bf16b(dw2[k * 256 + n]); return; } i -= 65536;
            if (i < 65536){ int n = i >> 8, k = i & 255; gw1T[i] = bf16b(gw1[k * 256 + n]); return; } i -= 65536;
            if (i < 65536){ int n = i >> 8, k = i & 255; gw2T[i] = bf16b(gw2[k * 256 + n]); return; } i -= 65536;
            if (i < 65536){ int n = i >> 8, k = i & 255; lwT[i]  = bf16b(lw[k * 256 + n]); return; }
            return;
        }
        // cvt_points: 2048 blocks x 512 thr x 4 elems = 8*4096*128
        int i = ((aux - 704) * 512 + t) * 4;
        f32x4 v = *(const f32x4*)(pts + i);
        ull pk = (ull)bf16b(v[0]) | (((ull)bf16b(v[1])) << 16)
               | (((ull)bf16b(v[2])) << 32) | (((ull)bf16b(v[3])) << 48);
        *(ull*)(pts16 + i) = pk;
        return;
    }

    // ---- FPS (blocks 0..7) ----
    int b = blk;
    int lane = t & 63, wvi = t >> 6;
    for (int p = t; p < 4096; p += 512){
        const float* s = xyz + ((size_t)b * 4096 + p) * 3;
        sx[p] = s[0]; sy[p] = s[1]; sz[p] = s[2];
    }
    __syncthreads();
    float px[8], py[8], pz[8], dist[8];
    unsigned nplo[8];
#pragma unroll
    for (int j = 0; j < 8; j++){
        int p = t + (j << 9);
        px[j] = sx[p]; py[j] = sy[p]; pz[j] = sz[p];
        dist[j] = 1e10f;
        nplo[j] = ~(unsigned)p;
        // pin in VGPRs: value becomes opaque -> no LDS rematerialization
        asm volatile("" : "+v"(px[j]), "+v"(py[j]), "+v"(pz[j]), "+v"(nplo[j]));
    }
    int far = 0;
    float cx = sx[0], cy = sy[0], cz = sz[0];
    int par = 0;
    for (int s = 0; s < 1024; s++){
        if (t == 0) farS[s] = far;
        ull lb = 0;
#pragma unroll
        for (int j = 0; j < 8; j++){
            float dx = __fsub_rn(px[j], cx);
            float dy = __fsub_rn(py[j], cy);
            float dz = __fsub_rn(pz[j], cz);
            float d = __fadd_rn(__fadd_rn(__fmul_rn(dx, dx), __fmul_rn(dy, dy)), __fmul_rn(dz, dz));
            float nd = fminf(dist[j], d);
            dist[j] = nd;
            ull k2 = (((ull)__float_as_uint(nd)) << 32) | nplo[j];
            if (k2 > lb) lb = k2;
        }
        // wave max (6 stages; lane63 holds the result)
        DPPMAX(lb, 0xB1); DPPMAX(lb, 0x4E); DPPMAX(lb, 0x141);
        DPPMAX(lb, 0x140); DPPMAX(lb, 0x142); DPPMAX(lb, 0x143);
        if (lane == 63) slotK[par][wvi] = lb;
        __syncthreads();
        // cross-wave: lane l reads slot[l&7]; 3-stage DPP max over each 8-group
        ull k = slotK[par][lane & 7];
        DPPMAX(k, 0xB1); DPPMAX(k, 0x4E); DPPMAX(k, 0x141);
        far = (int)(~(unsigned)k);
        cx = sx[far]; cy = sy[far]; cz = sz[far];
        par ^= 1;
    }
    // write outputs once (off the serial critical path)
    float* outp = nxyz_out + (size_t)b * 3072;
    for (int s2 = t; s2 < 1024; s2 += 512){
        int f = farS[s2];
        fps_idx[b * 1024 + s2] = f;
        outp[s2 * 3 + 0] = sx[f];
        outp[s2 * 3 + 1] = sy[f];
        outp[s2 * 3 + 2] = sz[f];
    }
}

// ---------- kernel 2: KNN (16 smallest d2 per sampled point) ----------
__global__ __launch_bounds__(256) void knn_kernel(const float* __restrict__ xyz,
                                                  const float* __restrict__ nxyz,
                                                  int* __restrict__ knn_idx)
{
    __shared__ float d2s[4096];
    __shared__ ull kslot[4];
    int G = blockIdx.x; int b = G >> 10;
    int t = threadIdx.x, lane = t & 63, wvi = t >> 6;
    float qx = nxyz[(size_t)G * 3], qy = nxyz[(size_t)G * 3 + 1], qz = nxyz[(size_t)G * 3 + 2];
    float qq = qx * qx + qy * qy + qz * qz;
    for (int j = 0; j < 16; j++){
        int p = t + (j << 8);
        const float* s = xyz + ((size_t)b * 4096 + p) * 3;
        float x = s[0], y = s[1], z = s[2];
        d2s[p] = qq - 2.f * (qx * x + qy * y + qz * z) + (x * x + y * y + z * z);
    }
    __syncthreads();
    for (int r = 0; r < 16; r++){
        ull best = ~0ull;
#pragma unroll
        for (int j = 0; j < 16; j++){
            int p = t + (j << 8);
            unsigned bb = __float_as_uint(d2s[p]);
            bb = (bb & 0x80000000u) ? ~bb : (bb | 0x80000000u);
            ull key = (((ull)bb) << 32) | (unsigned)p;
            if (key < best) best = key;
        }
        DPPMIN(best, 0xB1); DPPMIN(best, 0x4E); DPPMIN(best, 0x141);
        DPPMIN(best, 0x140); DPPMIN(best, 0x142); DPPMIN(best, 0x143);
        if (lane == 63) kslot[wvi] = best;
        __syncthreads();
        if (t == 0){
            ull bk = kslot[0];
            for (int w = 1; w < 4; w++) if (kslot[w] < bk) bk = kslot[w];
            int p = (int)(unsigned)bk;
            knn_idx[(size_t)G * 16 + r] = p;
            d2s[p] = 3.0e38f;
        }
        __syncthreads();
    }
}

// ---------- kernel 3: q = sampled_points @ wq (f32) ----------
__global__ __launch_bounds__(256) void q_kernel(const float* __restrict__ points,
                                                const float* __restrict__ wqT,
                                                const int* __restrict__ fps_idx,
                                                float* __restrict__ qbuf)
{
    __shared__ float sp[8][128];
    int t = threadIdx.x;
    int g0 = blockIdx.x * 8;
    {
        int r = t >> 5, c = (t & 31) * 4;
        int G = g0 + r; int b = G >> 10; int p = fps_idx[G];
        const f32x4 v = *(const f32x4*)(points + ((size_t)b * 4096 + p) * 128 + c);
        *(f32x4*)&sp[r][c] = v;
    }
    __syncthreads();
    float acc[8] = {0.f,0.f,0.f,0.f,0.f,0.f,0.f,0.f};
    const float* wr = wqT + t * 128;
    for (int k = 0; k < 128; k += 4){
        f32x4 w = *(const f32x4*)(wr + k);
#pragma unroll
        for (int r = 0; r < 8; r++)
            acc[r] += w[0]*sp[r][k] + w[1]*sp[r][k+1] + w[2]*sp[r][k+2] + w[3]*sp[r][k+3];
    }
#pragma unroll
    for (int r = 0; r < 8; r++) qbuf[(size_t)(g0 + r) * 256 + t] = acc[r];
}

// ---------- kernel 4: fused attention stack (4 groups / block) ----------
__global__ __launch_bounds__(256, 2) void fused_attn(
    const unsigned short* __restrict__ pts16,
    const float* __restrict__ xyz, const float* __restrict__ nxyz,
    const int* __restrict__ knn_idx, const float* __restrict__ qbuf,
    const unsigned short* __restrict__ wkT, const unsigned short* __restrict__ wvT,
    const unsigned short* __restrict__ dw2T, const unsigned short* __restrict__ gw1T,
    const unsigned short* __restrict__ gw2T,
    const float* __restrict__ dw1, const float* __restrict__ db1,
    const float* __restrict__ db2, const float* __restrict__ gb1, const float* __restrict__ gb2,
    unsigned short* __restrict__ resY)
{
    __shared__ unsigned short bufA[16384];  // pos1 -> t -> a1 -> e   [64][256] swz<8>
    __shared__ unsigned short bufU[16384];  // ptsA(swz<4>) -> u(swz<8>)
    int t = threadIdx.x, lane = t & 63, wave = t >> 6;
    int i = lane & 15, q = lane >> 4;
    int G0 = blockIdx.x * 4;
    int ch0 = wave * 64;
    unsigned short* ptsA = bufU;
    float* dw1s  = (float*)(bufU + 8192);   // 768 f32
    float* db1s  = (float*)(bufU + 9728);   // 256 f32
    float* xyznS = (float*)(bufU + 10240);  // 192 f32
    int*   idxs  = (int*)  (bufU + 10624);  // 64 int

    // stage 0: indices + pos-mlp layer-1 params
    if (t < 64) idxs[t] = knn_idx[G0 * 16 + t];
    dw1s[t] = dw1[t]; dw1s[256 + t] = dw1[256 + t]; dw1s[512 + t] = dw1[512 + t];
    db1s[t] = db1[t];
    __syncthreads();

    // stage 1: centered coords + gather neighbor features
    if (t < 64){
        int G = G0 + (t >> 4); int bb = G >> 10; int p = idxs[t];
        const float* xp = xyz + ((size_t)bb * 4096 + p) * 3;
        const float* nz = nxyz + (size_t)G * 3;
        xyznS[t * 3 + 0] = xp[0] - nz[0];
        xyznS[t * 3 + 1] = xp[1] - nz[1];
        xyznS[t * 3 + 2] = xp[2] - nz[2];
    }
    {
        int r = t >> 2, seg = t & 3;
        int G = G0 + (r >> 4); int bb = G >> 10; int p = idxs[r];
        const uint4* src = (const uint4*)(pts16 + ((size_t)bb * 4096 + p) * 128 + seg * 32);
#pragma unroll
        for (int j = 0; j < 4; j++){
            uint4 v = src[j];
            *(uint4*)(ptsA + swz<4>(r, seg * 32 + j * 8)) = v;
        }
    }
    __syncthreads();

    // stage 2: pos1 = relu(xyzn @ dw1 + db1) -> bufA
    {
        int r = lane;
        int o0 = wave * 64;
        float x = xyznS[r * 3], y = xyznS[r * 3 + 1], z = xyznS[r * 3 + 2];
#pragma unroll
        for (int j = 0; j < 64; j += 4){
            int o = o0 + j;
            f32x4 v;
#pragma unroll
            for (int e = 0; e < 4; e++)
                v[e] = fmaxf(db1s[o + e] + x * dw1s[o + e] + y * dw1s[256 + o + e] + z * dw1s[512 + o + e], 0.f);
            st4(bufA + swz<8>(r, o), v);
        }
    }
    __syncthreads();

    // stage 3: pos2 (P) and K GEMMs
    f32x4 accP[4][4]; ZERO44(accP);
    gemmT<8>(dw2T, bufA, ch0, lane, accP);
#pragma unroll
    for (int mt = 0; mt < 4; mt++){
        f32x4 d2v = *(const f32x4*)(db2 + ch0 + mt * 16 + q * 4);
#pragma unroll
        for (int nt = 0; nt < 4; nt++) accP[mt][nt] += d2v;
    }
    f32x4 accK[4][4]; ZERO44(accK);
    gemmT<4>(wkT, ptsA, ch0, lane, accK);
    __syncthreads();                     // pos1 reads complete

    // stage 4: t = q - k + pos  -> bufA ; then V GEMM
#pragma unroll
    for (int mt = 0; mt < 4; mt++){
        int c = ch0 + mt * 16 + q * 4;
#pragma unroll
        for (int nt = 0; nt < 4; nt++){
            int r = nt * 16 + i;
            f32x4 qv = *(const f32x4*)(qbuf + (size_t)(G0 + nt) * 256 + c);
            f32x4 tv = qv - accK[mt][nt] + accP[mt][nt];
            st4(bufA + swz<8>(r, c), tv);
        }
    }
    f32x4 accV[4][4]; ZERO44(accV);
    gemmT<4>(wvT, ptsA, ch0, lane, accV);
    __syncthreads();                     // t visible; ptsA reads complete

    // stage 5: u = v + pos -> bufU ; att1 GEMM on t
#pragma unroll
    for (int mt = 0; mt < 4; mt++){
        int c = ch0 + mt * 16 + q * 4;
#pragma unroll
        for (int nt = 0; nt < 4; nt++){
            int r = nt * 16 + i;
            f32x4 uv = accV[mt][nt] + accP[mt][nt];
            st4(bufU + swz<8>(r, c), uv);
        }
    }
    f32x4 acc1[4][4]; ZERO44(acc1);
    gemmT<8>(gw1T, bufA, ch0, lane, acc1);
    __syncthreads();                     // t reads complete; u visible

    // stage 6: a1 = relu(. + gb1) -> bufA
#pragma unroll
    for (int mt = 0; mt < 4; mt++){
        int c = ch0 + mt * 16 + q * 4;
        f32x4 g1v = *(const f32x4*)(gb1 + c);
#pragma unroll
        for (int nt = 0; nt < 4; nt++){
            int r = nt * 16 + i;
            f32x4 av = acc1[mt][nt] + g1v;
#pragma unroll
            for (int e = 0; e < 4; e++) av[e] = fmaxf(av[e], 0.f);
            st4(bufA + swz<8>(r, c), av);
        }
    }
    __syncthreads();                     // a1 visible

    // stage 7: att2 GEMM
    f32x4 acc2[4][4]; ZERO44(acc2);
    gemmT<8>(gw2T, bufA, ch0, lane, acc2);
    __syncthreads();                     // a1 reads complete

    // stage 8: e = exp((att + gb2)/16) -> bufA  (values ~1.0, max-sub safely skipped)
#pragma unroll
    for (int mt = 0; mt < 4; mt++){
        int c = ch0 + mt * 16 + q * 4;
        f32x4 g2v = *(const f32x4*)(gb2 + c);
#pragma unroll
        for (int nt = 0; nt < 4; nt++){
            int r = nt * 16 + i;
            f32x4 ev;
#pragma unroll
            for (int e = 0; e < 4; e++) ev[e] = __expf((acc2[mt][nt][e] + g2v[e]) * 0.0625f);
            st4(bufA + swz<8>(r, c), ev);
        }
    }
    __syncthreads();                     // e visible

    // stage 9: softmax-weighted sum over the 16 neighbors of each group
    {
        int g = t >> 6, c4 = (t & 63) * 4;
        f32x4 num; num[0]=0.f;num[1]=0.f;num[2]=0.f;num[3]=0.f;
        f32x4 den = num;
#pragma unroll
        for (int rr = 0; rr < 16; rr++){
            int r = g * 16 + rr;
            f32x4 e4 = ld4(bufA + swz<8>(r, c4));
            f32x4 u4 = ld4(bufU + swz<8>(r, c4));
            num += e4 * u4;
            den += e4;
        }
        f32x4 rv = num / den;
        st4(resY + (size_t)(G0 + g) * 256 + c4, rv);
    }
}

// ---------- kernel 5: z = res @ lw + lb, + channel stats ----------
__global__ __launch_bounds__(256, 2) void z_gemm(const unsigned short* __restrict__ resY,
                                                 const unsigned short* __restrict__ lwT,
                                                 const float* __restrict__ lb,
                                                 float* __restrict__ zbuf,
                                                 float* __restrict__ stats)
{
    int t = threadIdx.x, lane = t & 63, wave = t >> 6;
    int i = lane & 15, q = lane >> 4;
    int row0 = blockIdx.x * 128;
    int ch0 = wave * 64;
    f32x4 acc[4][8];
#pragma unroll
    for (int mt = 0; mt < 4; mt++)
#pragma unroll
        for (int nt = 0; nt < 8; nt++){ acc[mt][nt][0]=0.f;acc[mt][nt][1]=0.f;acc[mt][nt][2]=0.f;acc[mt][nt][3]=0.f; }
#pragma unroll
    for (int kt = 0; kt < 8; kt++){
        int k0 = kt * 32 + q * 8;
        bf16x8 a[4], bb[8];
#pragma unroll
        for (int mt = 0; mt < 4; mt++)
            a[mt] = *(const bf16x8*)(lwT + (size_t)(ch0 + mt * 16 + i) * 256 + k0);
#pragma unroll
        for (int nt = 0; nt < 8; nt++)
            bb[nt] = *(const bf16x8*)(resY + (size_t)(row0 + nt * 16 + i) * 256 + k0);
#pragma unroll
        for (int mt = 0; mt < 4; mt++)
#pragma unroll
            for (int nt = 0; nt < 8; nt++)
                acc[mt][nt] = __builtin_amdgcn_mfma_f32_16x16x32_bf16(a[mt], bb[nt], acc[mt][nt], 0, 0, 0);
    }
    f32x4 s1[4], s2[4];
#pragma unroll
    for (int mt = 0; mt < 4; mt++){ s1[mt][0]=0.f;s1[mt][1]=0.f;s1[mt][2]=0.f;s1[mt][3]=0.f; s2[mt]=s1[mt]; }
#pragma unroll
    for (int mt = 0; mt < 4; mt++){
        int c = ch0 + mt * 16 + q * 4;
        f32x4 lb4 = *(const f32x4*)(lb + c);
#pragma unroll
        for (int nt = 0; nt < 8; nt++){
            int r = row0 + nt * 16 + i;
            f32x4 z = acc[mt][nt] + lb4;
            *(f32x4*)(zbuf + (size_t)r * 256 + c) = z;
            s1[mt] += z;
            s2[mt] += z * z;
        }
    }
    for (int m = 1; m < 16; m <<= 1){
#pragma unroll
        for (int mt = 0; mt < 4; mt++)
#pragma unroll
            for (int e = 0; e < 4; e++){
                s1[mt][e] += __shfl_xor(s1[mt][e], m);
                s2[mt][e] += __shfl_xor(s2[mt][e], m);
            }
    }
    if (i == 0){
#pragma unroll
        for (int mt = 0; mt < 4; mt++){
            int c = ch0 + mt * 16 + q * 4;
#pragma unroll
            for (int e = 0; e < 4; e++){
                atomicAdd(&stats[c + e], s1[mt][e]);
                atomicAdd(&stats[256 + c + e], s2[mt][e]);
            }
        }
    }
}

// ---------- kernel 6: BN (batch stats) + ReLU ----------
__global__ __launch_bounds__(256) void bn_kernel(const float* __restrict__ zbuf,
                                                 const float* __restrict__ stats,
                                                 const float* __restrict__ bn_g,
                                                 const float* __restrict__ bn_b,
                                                 float* __restrict__ out)
{
    int G = blockIdx.x, c = threadIdx.x;
    float mean = stats[c] * (1.f / 8192.f);
    float var = stats[256 + c] * (1.f / 8192.f) - mean * mean;
    float inv = rsqrtf(var + 1e-5f);
    float z = zbuf[(size_t)G * 256 + c];
    float y = bn_g[c] * (z - mean) * inv + bn_b[c];
    out[24576 + (size_t)G * 256 + c] = fmaxf(y, 0.f);
}

// ---------- launch ----------
extern "C" void kernel_launch(void* const* d_in, const int* in_sizes, int n_in,
                              void* d_out, int out_size, void* d_ws, size_t ws_size,
                              hipStream_t stream)
{
    const float* xyz    = (const float*)d_in[0];
    const float* points = (const float*)d_in[1];
    const float* wq  = (const float*)d_in[2];
    const float* wk  = (const float*)d_in[3];
    const float* wv  = (const float*)d_in[4];
    const float* dw1 = (const float*)d_in[5];
    const float* db1 = (const float*)d_in[6];
    const float* dw2 = (const float*)d_in[7];
    const float* db2 = (const float*)d_in[8];
    const float* gw1 = (const float*)d_in[9];
    const float* gb1 = (const float*)d_in[10];
    const float* gw2 = (const float*)d_in[11];
    const float* gb2 = (const float*)d_in[12];
    const float* lw  = (const float*)d_in[13];
    const float* lb  = (const float*)d_in[14];
    const float* bn_g = (const float*)d_in[15];
    const float* bn_b = (const float*)d_in[16];
    float* out = (float*)d_out;

    char* ws = (char*)d_ws;
    int*            fps_idx = (int*)(ws + 0);
    int*            knn_idx = (int*)(ws + 32768);
    float*          qbuf    = (float*)(ws + 557056);
    unsigned short* pts16   = (unsigned short*)(ws + 8945664);
    unsigned short* wkT     = (unsigned short*)(ws + 17334272);
    unsigned short* wvT     = (unsigned short*)(ws + 17399808);
    unsigned short* dw2T    = (unsigned short*)(ws + 17465344);
    unsigned short* gw1T    = (unsigned short*)(ws + 17596416);
    unsigned short* gw2T    = (unsigned short*)(ws + 17727488);
    unsigned short* lwT     = (unsigned short*)(ws + 17858560);
    float*          wqT     = (float*)(ws + 17989632);
    unsigned short* resY    = (unsigned short*)(ws + 18120704);
    float*          zbuf    = (float*)(ws + 22315008);
    float*          stats   = (float*)(ws + 30703616);

    // blocks: 8 FPS + 704 prep (incl stats zero) + 2048 cvt = 2760
    fps_mega<<<2760, 512, 0, stream>>>(xyz, out, fps_idx, points, pts16,
                                       wq, wk, wv, dw2, gw1, gw2, lw,
                                       wqT, wkT, wvT, dw2T, gw1T, gw2T, lwT, stats);
    knn_kernel<<<8192, 256, 0, stream>>>(xyz, out, knn_idx);
    q_kernel<<<1024, 256, 0, stream>>>(points, wqT, fps_idx, qbuf);
    fused_attn<<<2048, 256, 0, stream>>>(pts16, xyz, out, knn_idx, qbuf,
                                         wkT, wvT, dw2T, gw1T, gw2T,
                                         dw1, db1, db2, gb1, gb2, resY);
    z_gemm<<<64, 256, 0, stream>>>(resY, lwT, lb, zbuf, stats);
    bn_kernel<<<8192, 256, 0, stream>>>(zbuf, stats, bn_g, bn_b, out);
}